// Round 15
// baseline (300.970 us; speedup 1.0000x reference)
//
#include <hip/hip_runtime.h>

#define DEV __device__ __forceinline__

typedef short bf16x8 __attribute__((ext_vector_type(8)));
typedef float f32x4 __attribute__((ext_vector_type(4)));

constexpr int BATCH = 16384, T = 64, H = 14;
constexpr float NL2E  = -1.4426950408889634f;   // -log2(e)
constexpr float N2L2E = -2.8853900817779268f;   // -2*log2(e)

union FragU { bf16x8 v; unsigned u[4]; };

template <int N> struct icx { static constexpr int value = N; };

struct __attribute__((packed, aligned(4))) u4u { uint4 v; };  // 4B-aligned 16B load

DEV unsigned cvtpk(float lo, float hi) {
  unsigned r;
  asm("v_cvt_pk_bf16_f32 %0, %1, %2" : "=v"(r) : "v"(lo), "v"(hi));
  return r;
}
DEV float pklo(unsigned u) { return __uint_as_float(u << 16); }
DEV float pkhi(unsigned u) { return __uint_as_float(u & 0xffff0000u); }

DEV f32x4 MFMA(FragU a, FragU b, f32x4 c) {
  return __builtin_amdgcn_mfma_f32_16x16x32_bf16(a.v, b.v, c, 0, 0, 0);
}

// One LSTM layer; one direction per blockIdx.y; one wave = SEQPW real
// sequences (A rows beyond SEQPW duplicate rows mod SEQPW). The cell-update
// epilogue is PARTITIONED across the duplicate q-groups: each lane computes
// VPL = SEQPW/4 cells (i = qs*VPL..), so doubling waves via duplication does
// NOT double per-SIMD epilogue issue -- MFMA work duplicates (7% utilized),
// transcendental work does not. h lives in an 8-slot LDS ring of bf16 planes;
// the ring IS the y staging buffer. Recurrent h-path: 1 MFMA per gate with
// B = [U1|U2] (2-component weight), A = [h1|h1]. x-path single-component;
// L1 keeps exact fp32 x via value|residual sections. Bias = MFMA C-operand.
// Weights/bias pre-scaled by -log2e (-2log2e for g). x prefetched 4-5 steps
// ahead; 8-step unrolled loop -> all LDS addresses immediate.
// INM: 0 = fp32 x [seq][t][13] (layer1) ; 1 = bf16 hi-plane x (layers 2,3)
// OUTM: 0 = bf16 hi-plane y (SEQPW=8) ; 1 = fp32 y [seq][t][14] (SEQPW=4)
template <int INM, int OUTM, int SEQPW>
__global__ __launch_bounds__(256, 4) void lstm_k(
    const float* __restrict__ xf,
    const unsigned short* __restrict__ xfh,
    const unsigned short* __restrict__ xbh,
    const float* __restrict__ wihF, const float* __restrict__ whhF,
    const float* __restrict__ bihF, const float* __restrict__ bhhF,
    const float* __restrict__ wihB, const float* __restrict__ whhB,
    const float* __restrict__ bihB, const float* __restrict__ bhhB,
    unsigned short* __restrict__ yFh, unsigned short* __restrict__ yBh,
    float* __restrict__ yf)
{
  constexpr int IN = (INM == 0) ? 13 : 28;
  constexpr int VPL = SEQPW / 4;          // cells per lane
  const int dir = (OUTM == 1) ? 0 : blockIdx.y;
  const float* __restrict__ wih = dir ? wihB : wihF;
  const float* __restrict__ whh = dir ? whhB : whhF;
  const float* __restrict__ bih = dir ? bihB : bihF;
  const float* __restrict__ bhh = dir ? bhhB : bhhF;
  unsigned short* __restrict__ yhiP = dir ? yBh : yFh;

  const int tid = threadIdx.x;
  const int w = tid >> 6, lane = tid & 63;
  const int col = lane & 15, q = lane >> 4;
  const int qodd = q & 1, qhi = q >> 1;
  const int scol = col & (SEQPW - 1);
  const bool jv = col < H;
  const int jc = jv ? col : 13;
  const int qe = q & (VPL - 1);           // seq-quad selector (rows 4qe..)
  const int qs = q / (VPL == 0 ? 1 : VPL);// epilogue split index
  const int i0 = qs * VPL;                // this lane's first cell index

  // ring: [wave][slot 0..7][seq][ hc1 dw0..7 | pad dw8..11 ]
  __shared__ unsigned ringS[4][8][SEQPW][12];
  __shared__ __align__(16) float fst_s[OUTM == 1 ? 4 * SEQPW * 112 : 4];
  unsigned* const ringD = &ringS[0][0][0][0];
  unsigned short* const ringU = (unsigned short*)ringD;
  float* const fstw = fst_s + ((OUTM == 1) ? w * (SEQPW * 112) : 0);

  {  // zero the WHOLE per-wave ring (slot 7 = step-0 h; ch 14/15 stay 0
     // forever: they feed MFMAs against zero B-cols and flush to y planes)
    unsigned* rz = ringD + (unsigned)(w * 8 * SEQPW) * 12u;
    for (int i = lane; i < 8 * SEQPW * 12; i += 64) rz[i] = 0u;
  }

  // ---------------- B fragments + fp32 bias C0 (built once) ----------------
  FragU Bx1[4], Bh1[4];
  f32x4 bbq[4];
#pragma unroll
  for (int g = 0; g < 4; ++g) {
    const int grow = g * H + jc;
    const float sc = (g == 2) ? N2L2E : NL2E;
    const float bsc = jv ? (bih[grow] + bhh[grow]) * sc : 0.f;
    bbq[g] = (f32x4){bsc, bsc, bsc, bsc};
    const float* __restrict__ wr = wih + grow * IN;
    const float* __restrict__ ur = whh + grow * H;
#pragma unroll
    for (int p = 0; p < 4; ++p) {
      {  // x weights: single component W1
        float wa = 0.f, wb = 0.f;
        const int l0 = 8 * qodd + 2 * p;
        if (INM == 0) {  // 13 ch; sec0 = x values, sec1 = x residuals (same W1)
          if (jv && l0 < 13) wa = wr[l0] * sc;
          if (jv && l0 + 1 < 13) wb = wr[l0 + 1] * sc;
        } else {         // plane-local ch; wih col = qhi*14 + l
          if (jv && l0 < 14) wa = wr[qhi * 14 + l0] * sc;
          if (jv && l0 + 1 < 14) wb = wr[qhi * 14 + l0 + 1] * sc;
        }
        Bx1[g].u[p] = cvtpk(wa, wb);
      }
      {  // h weights: sec0 (q<2) carries U1, sec1 (q>=2) carries U2 residual
        const int m0 = 8 * qodd + 2 * p;
        const float ua = (jv && m0 < 14) ? ur[m0] * sc : 0.f;
        const float ub = (jv && (m0 + 1) < 14) ? ur[m0 + 1] * sc : 0.f;
        const unsigned c1 = cvtpk(ua, ub);
        const float ra = ua - pklo(c1), rb = ub - pkhi(c1);
        const unsigned c2 = cvtpk(ra, rb);
        Bh1[g].u[p] = qhi ? c2 : c1;
      }
    }
  }

  const unsigned sb = (unsigned)blockIdx.x * (4u * SEQPW) + (unsigned)w * SEQPW;
  const unsigned arow = sb + (unsigned)scol;

  // LDS bases (all per-step addresses = base + compile-time immediate).
  const unsigned rdBase =
      ((unsigned)(w * 8) * SEQPW + (unsigned)scol) * 12u + (unsigned)(qodd * 4);
  const unsigned wrBase =
      ((unsigned)(w * 8) * SEQPW + (unsigned)(4 * qe)) * 24u + (unsigned)col;

  const int t0 = dir ? T - 1 : 0;
  const int dsx = (INM == 0) ? (dir ? -52 : 52) : (dir ? -32 : 32);
  int voff0;
  if constexpr (INM == 0)
    voff0 = (int)((arow * 64u + (unsigned)t0) * 52u) + qodd * 32;
  else
    voff0 = (int)((arow * 64u + (unsigned)t0) * 32u) + qodd * 16;
  const unsigned short* __restrict__ xph = (INM == 0) ? nullptr : (qhi ? xbh : xfh);

  float cc[VPL];
#pragma unroll
  for (int m = 0; m < VPL; ++m) cc[m] = 0.f;

  auto loadf = [&](float (&dst)[8], int off) {
    const char* pa = (const char*)xf + off;
    if (!qodd) {  // floats 0..7: two 4B-aligned 16B loads
      const uint4 a = ((const u4u*)pa)->v;
      const uint4 b = ((const u4u*)(pa + 16))->v;
      dst[0] = __uint_as_float(a.x); dst[1] = __uint_as_float(a.y);
      dst[2] = __uint_as_float(a.z); dst[3] = __uint_as_float(a.w);
      dst[4] = __uint_as_float(b.x); dst[5] = __uint_as_float(b.y);
      dst[6] = __uint_as_float(b.z); dst[7] = __uint_as_float(b.w);
    } else {      // floats 8..12 valid; clamp tail (B-side zeros kill clones)
      const uint4 a = ((const u4u*)pa)->v;
      dst[0] = __uint_as_float(a.x); dst[1] = __uint_as_float(a.y);
      dst[2] = __uint_as_float(a.z); dst[3] = __uint_as_float(a.w);
      dst[4] = *(const float*)(pa + 16);
      dst[5] = dst[6] = dst[7] = dst[4];
    }
  };
  auto loadu = [&](unsigned (&dst)[4], int off) {
    const uint4 a = *(const uint4*)((const char*)xph + off);
    dst[0] = a.x; dst[1] = a.y; dst[2] = a.z; dst[3] = a.w;
  };
  auto LOADX = [&](float (&df)[8], unsigned (&du)[4], int off) {
    if constexpr (INM == 0) loadf(df, off); else loadu(du, off);
  };

  // x-side MFMA block (independent of h): ax = bias + x*W1
  auto XCALC = [&](float (&xfb)[8], unsigned (&xub)[4], f32x4 (&ax)[4]) {
    FragU Ax1;
    if constexpr (INM == 0) {
      unsigned c[4];
#pragma unroll
      for (int p = 0; p < 4; ++p) c[p] = cvtpk(xfb[2 * p], xfb[2 * p + 1]);
      if (qhi) {  // sec1 lanes carry the residual component
#pragma unroll
        for (int p = 0; p < 4; ++p) {
          const float ra = xfb[2 * p] - pklo(c[p]);
          const float rb = xfb[2 * p + 1] - pkhi(c[p]);
          c[p] = cvtpk(ra, rb);
        }
      }
#pragma unroll
      for (int p = 0; p < 4; ++p) Ax1.u[p] = c[p];
    } else {
#pragma unroll
      for (int p = 0; p < 4; ++p) Ax1.u[p] = xub[p];
    }
#pragma unroll
    for (int g = 0; g < 4; ++g)
      ax[g] = MFMA(Ax1, Bx1[g], bbq[g]);  // bias + x*W1 (L1: exact-x * W1)
  };

  // One recurrent step. J = compile-time slot index (step s+J, s%8==0).
  auto STEP = [&](auto Jc, float (&nf)[8], unsigned (&nu)[4],
                  f32x4 (&cur)[4], f32x4 (&nxt)[4]) {
    constexpr int J = decltype(Jc)::value;
    constexpr int SLOT_R = (J + 7) & 7;
    // 1. h fragment from ring (single b128, broadcast across q-groups)
    FragU A12;
    {
      const uint4 t4 =
          *(const uint4*)(ringD + rdBase + (unsigned)(SLOT_R * SEQPW * 12));
      A12.u[0] = t4.x; A12.u[1] = t4.y; A12.u[2] = t4.z; A12.u[3] = t4.w;
    }
    // 2. next step's x block (fills the ds_read shadow)
    XCALC(nf, nu, nxt);
    // 3. h-chain: ONE MFMA per gate -> z = ax + h1*(U1+U2)
    f32x4 z[4];
#pragma unroll
    for (int g = 0; g < 4; ++g)
      z[g] = MFMA(A12, Bh1[g], cur[g]);
    // 4. activations, SPLIT across duplicate q-groups: this lane does cells
    //    i = i0 .. i0+VPL-1 only (pre-scaled: z' = -log2e*z ; g: -2log2e*z)
#pragma unroll
    for (int m = 0; m < VPL; ++m) {
      const int i = i0 + m;
      const float zi = z[0][i], zf = z[1][i], zg = z[2][i], zo = z[3][i];
      const float Ei = __builtin_amdgcn_exp2f(zi);
      const float Ef = __builtin_amdgcn_exp2f(zf);
      const float Eo = __builtin_amdgcn_exp2f(zo);
      const float Eg = __builtin_amdgcn_exp2f(-fabsf(zg));
      const float Pig = (1.f + Ei) * (1.f + Eg);
      const float F = 1.f + Ef;
      const float t2 = (1.f - Eg) * F;
      const float t2s =
          copysignf(t2, __uint_as_float(__float_as_uint(zg) ^ 0x80000000u));
      const float cn = fmaf(cc[m], Pig, t2s) * __builtin_amdgcn_rcpf(F * Pig);
      cc[m] = cn;
      const float Ec = __builtin_amdgcn_exp2f(fabsf(cn) * N2L2E);
      float hn = (1.f - Ec) * __builtin_amdgcn_rcpf((1.f + Eo) * (1.f + Ec));
      hn = copysignf(hn, cn);
      const unsigned c1 = cvtpk(hn, hn);          // bf16 h (both halves)
      if (jv) {
        ringU[wrBase + (unsigned)(J * SEQPW * 24 + i * 24)] = (unsigned short)c1;
        if constexpr (OUTM == 1)
          fstw[(4 * qe + i) * 112 + J * 14 + col] = hn;
      }
    }
  };

  // flush ring -> global bf16 hi plane (full 64B lines). SEQPW=8: 64 rows of
  // 32B, one per lane.
  auto flushY8 = [&](int sBase) {
    const int sq = lane >> 3, r = lane & 7;   // seq, slot
    const int tg = dir ? (63 - (sBase + r)) : (sBase + r);
    const unsigned* src =
        ringD + ((unsigned)(w * 8 + r) * SEQPW + (unsigned)sq) * 12u;
    const uint4 h0 = *(const uint4*)(src);
    const uint4 h1 = *(const uint4*)(src + 4);
    char* gph = (char*)yhiP + ((sb + (unsigned)sq) * 64u + (unsigned)tg) * 32u;
    *(uint4*)(gph) = h0; *(uint4*)(gph + 16) = h1;
  };
  auto flushO = [&](int tbase) {  // fp32 out (SEQPW=4): 448B/seq contiguous
    const int sq = lane >> 4, part = lane & 15;
    char* gp = (char*)yf + ((sb + (unsigned)sq) * 64u + (unsigned)tbase) * 56u;
    const float* src = fstw + sq * 112 + part;
#pragma unroll
    for (int m = 0; m < 7; ++m)
      *(float*)(gp + (part + 16 * m) * 4) = src[16 * m];
  };

  // x offset for step index k (clamped at the tail; clamped loads feed only
  // dead XCALC results)
  auto XO = [&](int k) { return voff0 + (k > 63 ? 63 : k) * dsx; };

  float fb0[8], fb1[8], fb2[8], fb3[8], fb4[8], fb5[8], fb6[8], fb7[8];
  unsigned ub0[4], ub1[4], ub2[4], ub3[4], ub4[4], ub5[4], ub6[4], ub7[4];
  f32x4 axP[4], axQ[4];

  LOADX(fb0, ub0, XO(0));
  LOADX(fb1, ub1, XO(1));
  LOADX(fb2, ub2, XO(2));
  LOADX(fb3, ub3, XO(3));
  LOADX(fb4, ub4, XO(4));
  XCALC(fb0, ub0, axP);  // ax for step 0

#pragma unroll 1
  for (int s = 0; s < T; s += 8) {
    LOADX(fb5, ub5, XO(s + 5));
    LOADX(fb6, ub6, XO(s + 6));
    STEP(icx<0>{}, fb1, ub1, axP, axQ);
    STEP(icx<1>{}, fb2, ub2, axQ, axP);
    LOADX(fb7, ub7, XO(s + 7));
    LOADX(fb0, ub0, XO(s + 8));
    STEP(icx<2>{}, fb3, ub3, axP, axQ);
    STEP(icx<3>{}, fb4, ub4, axQ, axP);
    LOADX(fb1, ub1, XO(s + 9));
    LOADX(fb2, ub2, XO(s + 10));
    STEP(icx<4>{}, fb5, ub5, axP, axQ);
    STEP(icx<5>{}, fb6, ub6, axQ, axP);
    LOADX(fb3, ub3, XO(s + 11));
    LOADX(fb4, ub4, XO(s + 12));
    STEP(icx<6>{}, fb7, ub7, axP, axQ);
    STEP(icx<7>{}, fb0, ub0, axQ, axP);
    if constexpr (OUTM == 0) flushY8(s); else flushO(s);
  }
}

extern "C" void kernel_launch(void* const* d_in, const int* in_sizes, int n_in,
                              void* d_out, int out_size, void* d_ws, size_t ws_size,
                              hipStream_t stream) {
  const float* x     = (const float*)d_in[0];
  const float* wih1f = (const float*)d_in[1];
  const float* whh1f = (const float*)d_in[2];
  const float* bih1f = (const float*)d_in[3];
  const float* bhh1f = (const float*)d_in[4];
  const float* wih1b = (const float*)d_in[5];
  const float* whh1b = (const float*)d_in[6];
  const float* bih1b = (const float*)d_in[7];
  const float* bhh1b = (const float*)d_in[8];
  const float* wih2f = (const float*)d_in[9];
  const float* whh2f = (const float*)d_in[10];
  const float* bih2f = (const float*)d_in[11];
  const float* bhh2f = (const float*)d_in[12];
  const float* wih2b = (const float*)d_in[13];
  const float* whh2b = (const float*)d_in[14];
  const float* bih2b = (const float*)d_in[15];
  const float* bhh2b = (const float*)d_in[16];
  const float* wih3  = (const float*)d_in[17];
  const float* whh3  = (const float*)d_in[18];
  const float* bih3  = (const float*)d_in[19];
  const float* bhh3  = (const float*)d_in[20];

  using usp = unsigned short*;
  const size_t PL = (size_t)BATCH * T * 16;  // ushorts per plane (padded 16ch)
  usp y1fh = (usp)d_ws;
  usp y1bh = y1fh + PL;
  usp y2fh = y1bh + PL;
  usp y2bh = y2fh + PL;
  float* out = (float*)d_out;

  const dim3 blk(256);
  const dim3 grid_bi(BATCH / 32, 2);   // SEQPW=8  -> 4096 waves = 4/SIMD
  const dim3 grid_uni(BATCH / 16, 1);  // SEQPW=4  -> 4096 waves = 4/SIMD

  lstm_k<0, 0, 8><<<grid_bi, blk, 0, stream>>>(
      x, nullptr, nullptr,
      wih1f, whh1f, bih1f, bhh1f, wih1b, whh1b, bih1b, bhh1b,
      y1fh, y1bh, nullptr);
  lstm_k<1, 0, 8><<<grid_bi, blk, 0, stream>>>(
      nullptr, y1fh, y1bh,
      wih2f, whh2f, bih2f, bhh2f, wih2b, whh2b, bih2b, bhh2b,
      y2fh, y2bh, nullptr);
  lstm_k<1, 1, 4><<<grid_uni, blk, 0, stream>>>(
      nullptr, y2fh, y2bh,
      wih3, whh3, bih3, bhh3, wih3, whh3, bih3, bhh3,
      nullptr, nullptr, out);
}

// Round 17
// 162.124 us; speedup vs baseline: 1.8564x; 1.8564x over previous
//
#include <hip/hip_runtime.h>

#define DEV __device__ __forceinline__

typedef short bf16x8 __attribute__((ext_vector_type(8)));
typedef float f32x4 __attribute__((ext_vector_type(4)));
typedef float f32x2 __attribute__((ext_vector_type(2)));

constexpr int BATCH = 16384, T = 64, H = 14;
constexpr float NL2E  = -1.4426950408889634f;   // -log2(e)
constexpr float N2L2E = -2.8853900817779268f;   // -2*log2(e)

union FragU { bf16x8 v; unsigned u[4]; };

template <int N> struct icx { static constexpr int value = N; };

struct __attribute__((packed, aligned(4))) u4u { uint4 v; };  // 4B-aligned 16B load

DEV unsigned cvtpk(float lo, float hi) {
  unsigned r;
  asm("v_cvt_pk_bf16_f32 %0, %1, %2" : "=v"(r) : "v"(lo), "v"(hi));
  return r;
}
DEV float pklo(unsigned u) { return __uint_as_float(u << 16); }
DEV float pkhi(unsigned u) { return __uint_as_float(u & 0xffff0000u); }

DEV f32x4 MFMA(FragU a, FragU b, f32x4 c) {
  return __builtin_amdgcn_mfma_f32_16x16x32_bf16(a.v, b.v, c, 0, 0, 0);
}

// One LSTM layer; one direction per blockIdx.y; one wave = SEQPW sequences.
// SEQPW=16: no duplication, each lane epilogues 4 cells (2 f32x2 pairs).
// SEQPW=8 (uni): rows 8-15 duplicate rows 0-7; the epilogue is split across
// the existing dup pair (qhi) -> half the transcendentals per wave at NO
// added MFMA/LDS/load work (R15 lesson: never duplicate work). Cell algebra
// uses NATIVE f32x2 vector arithmetic -- the compiler may lower to
// v_pk_*_f32 with correct register alignment (R16 lesson: no hand VOP3P).
// h lives in an 8-slot LDS ring of bf16 planes; the ring IS the y staging
// buffer. h-path: 1 MFMA per gate, B=[U1|U2], A=[h1|h1]. x-path single
// component; L1 keeps exact fp32 x via value|residual sections. Bias = MFMA
// C-operand. Weights/bias pre-scaled by -log2e (-2log2e for g). x prefetched
// 4-5 steps ahead; 8-step unrolled blocks with compile-time offsets (last
// block peeled for the tail clamp).
// INM: 0 = fp32 x [seq][t][13] (layer1) ; 1 = bf16 hi-plane x (layers 2,3)
// OUTM: 0 = bf16 hi-plane y (SEQPW=16) ; 1 = fp32 y [seq][t][14] (SEQPW=8)
template <int INM, int OUTM, int SEQPW>
__global__ __launch_bounds__(256, 2) void lstm_k(
    const float* __restrict__ xf,
    const unsigned short* __restrict__ xfh,
    const unsigned short* __restrict__ xbh,
    const float* __restrict__ wihF, const float* __restrict__ whhF,
    const float* __restrict__ bihF, const float* __restrict__ bhhF,
    const float* __restrict__ wihB, const float* __restrict__ whhB,
    const float* __restrict__ bihB, const float* __restrict__ bhhB,
    unsigned short* __restrict__ yFh, unsigned short* __restrict__ yBh,
    float* __restrict__ yf)
{
  constexpr int IN = (INM == 0) ? 13 : 28;
  constexpr int VPL = (SEQPW == 16) ? 4 : 2;  // cells per lane
  const int dir = (OUTM == 1) ? 0 : blockIdx.y;
  const float* __restrict__ wih = dir ? wihB : wihF;
  const float* __restrict__ whh = dir ? whhB : whhF;
  const float* __restrict__ bih = dir ? bihB : bihF;
  const float* __restrict__ bhh = dir ? bhhB : bhhF;
  unsigned short* __restrict__ yhiP = dir ? yBh : yFh;

  const int tid = threadIdx.x;
  const int w = tid >> 6, lane = tid & 63;
  const int col = lane & 15, q = lane >> 4;
  const int qodd = q & 1, qhi = q >> 1;
  const int scol = col & (SEQPW - 1);
  const bool jv = col < H;
  const int jc = jv ? col : 13;
  const int qe = (SEQPW == 16) ? q : (q & 1);
  const int i0 = (SEQPW == 16) ? 0 : 2 * qhi;   // first owned cell index

  // ring: [wave][slot 0..7][seq][ hc1 dw0..7 | pad dw8..11 ]
  __shared__ unsigned ringS[4][8][SEQPW][12];
  __shared__ __align__(16) float fst_s[OUTM == 1 ? 4 * SEQPW * 112 : 4];
  unsigned* const ringD = &ringS[0][0][0][0];
  unsigned short* const ringU = (unsigned short*)ringD;
  float* const fstw = fst_s + ((OUTM == 1) ? w * (SEQPW * 112) : 0);

  {  // zero the WHOLE per-wave ring (slot 7 = step-0 h; ch 14/15 stay 0
     // forever: they feed MFMAs against zero B-cols and flush to y planes)
    unsigned* rz = ringD + (unsigned)(w * 8 * SEQPW) * 12u;
    for (int i = lane; i < 8 * SEQPW * 12; i += 64) rz[i] = 0u;
  }

  // ---------------- B fragments + fp32 bias C0 (built once) ----------------
  FragU Bx1[4], Bh1[4];
  f32x4 bbq[4];
#pragma unroll
  for (int g = 0; g < 4; ++g) {
    const int grow = g * H + jc;
    const float sc = (g == 2) ? N2L2E : NL2E;
    const float bsc = jv ? (bih[grow] + bhh[grow]) * sc : 0.f;
    bbq[g] = (f32x4){bsc, bsc, bsc, bsc};
    const float* __restrict__ wr = wih + grow * IN;
    const float* __restrict__ ur = whh + grow * H;
#pragma unroll
    for (int p = 0; p < 4; ++p) {
      {  // x weights: single component W1
        float wa = 0.f, wb = 0.f;
        const int l0 = 8 * qodd + 2 * p;
        if (INM == 0) {  // 13 ch; sec0 = x values, sec1 = x residuals (same W1)
          if (jv && l0 < 13) wa = wr[l0] * sc;
          if (jv && l0 + 1 < 13) wb = wr[l0 + 1] * sc;
        } else {         // plane-local ch; wih col = qhi*14 + l
          if (jv && l0 < 14) wa = wr[qhi * 14 + l0] * sc;
          if (jv && l0 + 1 < 14) wb = wr[qhi * 14 + l0 + 1] * sc;
        }
        Bx1[g].u[p] = cvtpk(wa, wb);
      }
      {  // h weights: sec0 (q<2) carries U1, sec1 (q>=2) carries U2 residual
        const int m0 = 8 * qodd + 2 * p;
        const float ua = (jv && m0 < 14) ? ur[m0] * sc : 0.f;
        const float ub = (jv && (m0 + 1) < 14) ? ur[m0 + 1] * sc : 0.f;
        const unsigned c1 = cvtpk(ua, ub);
        const float ra = ua - pklo(c1), rb = ub - pkhi(c1);
        const unsigned c2 = cvtpk(ra, rb);
        Bh1[g].u[p] = qhi ? c2 : c1;
      }
    }
  }

  const unsigned sb = (unsigned)blockIdx.x * (4u * SEQPW) + (unsigned)w * SEQPW;
  const unsigned arow = sb + (unsigned)scol;

  // LDS bases (all per-step addresses = base + compile-time immediate).
  const unsigned rdBase =
      ((unsigned)(w * 8) * SEQPW + (unsigned)scol) * 12u + (unsigned)(qodd * 4);
  const unsigned wrBase =
      ((unsigned)(w * 8) * SEQPW + (unsigned)(4 * qe + i0)) * 24u + (unsigned)col;
  float* const fstE = fstw + (4 * qe + i0) * 112 + col;  // OUTM==1 only

  const int t0 = dir ? T - 1 : 0;
  const int dsx = (INM == 0) ? (dir ? -52 : 52) : (dir ? -32 : 32);
  int voff0;
  if constexpr (INM == 0)
    voff0 = (int)((arow * 64u + (unsigned)t0) * 52u) + qodd * 32;
  else
    voff0 = (int)((arow * 64u + (unsigned)t0) * 32u) + qodd * 16;
  const unsigned short* __restrict__ xph = (INM == 0) ? nullptr : (qhi ? xbh : xfh);

  const f32x2 one2 = {1.f, 1.f};
  f32x2 ccv[VPL / 2];
#pragma unroll
  for (int m = 0; m < VPL / 2; ++m) ccv[m] = (f32x2){0.f, 0.f};

  auto loadf = [&](float (&dst)[8], int off) {
    const char* pa = (const char*)xf + off;
    if (!qodd) {  // floats 0..7: two 4B-aligned 16B loads
      const uint4 a = ((const u4u*)pa)->v;
      const uint4 b = ((const u4u*)(pa + 16))->v;
      dst[0] = __uint_as_float(a.x); dst[1] = __uint_as_float(a.y);
      dst[2] = __uint_as_float(a.z); dst[3] = __uint_as_float(a.w);
      dst[4] = __uint_as_float(b.x); dst[5] = __uint_as_float(b.y);
      dst[6] = __uint_as_float(b.z); dst[7] = __uint_as_float(b.w);
    } else {      // floats 8..12 valid; clamp tail (B-side zeros kill clones)
      const uint4 a = ((const u4u*)pa)->v;
      dst[0] = __uint_as_float(a.x); dst[1] = __uint_as_float(a.y);
      dst[2] = __uint_as_float(a.z); dst[3] = __uint_as_float(a.w);
      dst[4] = *(const float*)(pa + 16);
      dst[5] = dst[6] = dst[7] = dst[4];
    }
  };
  auto loadu = [&](unsigned (&dst)[4], int off) {
    const uint4 a = *(const uint4*)((const char*)xph + off);
    dst[0] = a.x; dst[1] = a.y; dst[2] = a.z; dst[3] = a.w;
  };
  auto LOADX = [&](float (&df)[8], unsigned (&du)[4], int off) {
    if constexpr (INM == 0) loadf(df, off); else loadu(du, off);
  };

  // x-side MFMA block (independent of h): ax = bias + x*W1
  auto XCALC = [&](float (&xfb)[8], unsigned (&xub)[4], f32x4 (&ax)[4]) {
    FragU Ax1;
    if constexpr (INM == 0) {
      unsigned c[4];
#pragma unroll
      for (int p = 0; p < 4; ++p) c[p] = cvtpk(xfb[2 * p], xfb[2 * p + 1]);
      if (qhi) {  // sec1 lanes carry the residual component
#pragma unroll
        for (int p = 0; p < 4; ++p) {
          const float ra = xfb[2 * p] - pklo(c[p]);
          const float rb = xfb[2 * p + 1] - pkhi(c[p]);
          c[p] = cvtpk(ra, rb);
        }
      }
#pragma unroll
      for (int p = 0; p < 4; ++p) Ax1.u[p] = c[p];
    } else {
#pragma unroll
      for (int p = 0; p < 4; ++p) Ax1.u[p] = xub[p];
    }
#pragma unroll
    for (int g = 0; g < 4; ++g)
      ax[g] = MFMA(Ax1, Bx1[g], bbq[g]);  // bias + x*W1 (L1: exact-x * W1)
  };

  // select this lane's owned cell-pair from an accumulator (compile-time for
  // SEQPW=16; vector cndmask for SEQPW=8 -- NO dynamic ext_vector indexing)
  auto pick2 = [&](const f32x4& v, int m2) -> f32x2 {
    if constexpr (SEQPW == 16) {
      return (m2 == 0) ? (f32x2){v[0], v[1]} : (f32x2){v[2], v[3]};
    } else {
      const f32x2 lo = {v[0], v[1]}, hi = {v[2], v[3]};
      return qhi ? hi : lo;
    }
  };

  // One recurrent step. J = compile-time slot index (step s+J, s%8==0).
  auto STEP = [&](auto Jc, float (&nf)[8], unsigned (&nu)[4],
                  f32x4 (&cur)[4], f32x4 (&nxt)[4]) {
    constexpr int J = decltype(Jc)::value;
    constexpr int SLOT_R = (J + 7) & 7;
    // 1. h fragment from ring (single b128, broadcast across q-groups)
    FragU A12;
    {
      const uint4 t4 =
          *(const uint4*)(ringD + rdBase + (unsigned)(SLOT_R * SEQPW * 12));
      A12.u[0] = t4.x; A12.u[1] = t4.y; A12.u[2] = t4.z; A12.u[3] = t4.w;
    }
    // 2. next step's x block (fills the ds_read shadow)
    XCALC(nf, nu, nxt);
    // 3. h-chain: ONE MFMA per gate -> z = ax + h1*(U1+U2)
    f32x4 z[4];
#pragma unroll
    for (int g = 0; g < 4; ++g)
      z[g] = MFMA(A12, Bh1[g], cur[g]);
    // 4. cell update on owned pairs only (native f32x2 vector math; compiler
    //    may lower to v_pk_*_f32)
#pragma unroll
    for (int m2 = 0; m2 < VPL / 2; ++m2) {
      const f32x2 zi = pick2(z[0], m2), zf = pick2(z[1], m2);
      const f32x2 zg = pick2(z[2], m2), zo = pick2(z[3], m2);
      f32x2 Ei, Ef, Eo, Eg;
      Ei.x = __builtin_amdgcn_exp2f(zi.x); Ei.y = __builtin_amdgcn_exp2f(zi.y);
      Ef.x = __builtin_amdgcn_exp2f(zf.x); Ef.y = __builtin_amdgcn_exp2f(zf.y);
      Eo.x = __builtin_amdgcn_exp2f(zo.x); Eo.y = __builtin_amdgcn_exp2f(zo.y);
      Eg.x = __builtin_amdgcn_exp2f(-fabsf(zg.x));
      Eg.y = __builtin_amdgcn_exp2f(-fabsf(zg.y));
      const f32x2 Pig = (one2 + Ei) * (one2 + Eg);
      const f32x2 F = one2 + Ef;
      const f32x2 t2 = (one2 - Eg) * F;
      f32x2 t2s;
      t2s.x = copysignf(t2.x, __uint_as_float(__float_as_uint(zg.x) ^ 0x80000000u));
      t2s.y = copysignf(t2.y, __uint_as_float(__float_as_uint(zg.y) ^ 0x80000000u));
      const f32x2 num = ccv[m2] * Pig + t2s;
      const f32x2 FP = F * Pig;
      f32x2 rFP;
      rFP.x = __builtin_amdgcn_rcpf(FP.x); rFP.y = __builtin_amdgcn_rcpf(FP.y);
      const f32x2 cn = num * rFP;
      ccv[m2] = cn;
      f32x2 Ec;
      Ec.x = __builtin_amdgcn_exp2f(fabsf(cn.x) * N2L2E);
      Ec.y = __builtin_amdgcn_exp2f(fabsf(cn.y) * N2L2E);
      const f32x2 den = (one2 + Eo) * (one2 + Ec);
      f32x2 rd;
      rd.x = __builtin_amdgcn_rcpf(den.x); rd.y = __builtin_amdgcn_rcpf(den.y);
      const f32x2 hraw = (one2 - Ec) * rd;
      const float h0 = copysignf(hraw.x, cn.x);
      const float h1 = copysignf(hraw.y, cn.y);
      const unsigned c10 = cvtpk(h0, h0);
      const unsigned c11 = cvtpk(h1, h1);
      if (jv) {
        ringU[wrBase + (unsigned)(J * SEQPW * 24 + (2 * m2) * 24)]     = (unsigned short)c10;
        ringU[wrBase + (unsigned)(J * SEQPW * 24 + (2 * m2 + 1) * 24)] = (unsigned short)c11;
        if constexpr (OUTM == 1) {
          fstE[(2 * m2) * 112 + J * 14]     = h0;
          fstE[(2 * m2 + 1) * 112 + J * 14] = h1;
        }
      }
    }
  };

  // flush ring -> global bf16 hi plane (full 64B lines)
  auto flushY8 = [&](int sBase) {
    const int sq = lane >> 2, part = lane & 3;
#pragma unroll
    for (int rr = 0; rr < 2; ++rr) {
      const int r = 2 * part + rr;  // slot = step offset within the block
      const int tg = dir ? (63 - (sBase + r)) : (sBase + r);
      const unsigned* src =
          ringD + ((unsigned)(w * 8 + r) * SEQPW + (unsigned)sq) * 12u;
      const uint4 h0 = *(const uint4*)(src);
      const uint4 h1 = *(const uint4*)(src + 4);
      char* gph = (char*)yhiP + ((sb + (unsigned)sq) * 64u + (unsigned)tg) * 32u;
      *(uint4*)(gph) = h0; *(uint4*)(gph + 16) = h1;
    }
  };
  auto flushO = [&](int tbase) {  // fp32 out (SEQPW=8): 448B/seq contiguous
    const int sq = lane >> 3, part = lane & 7;
    char* gp = (char*)yf + ((sb + (unsigned)sq) * 64u + (unsigned)tbase) * 56u;
    const float* src = fstw + sq * 112 + part;
#pragma unroll
    for (int m = 0; m < 14; ++m)
      *(float*)(gp + (part + 8 * m) * 4) = src[8 * m];
  };

  float fb0[8], fb1[8], fb2[8], fb3[8], fb4[8], fb5[8], fb6[8], fb7[8];
  unsigned ub0[4], ub1[4], ub2[4], ub3[4], ub4[4], ub5[4], ub6[4], ub7[4];
  f32x4 axP[4], axQ[4];

  int vb = voff0;
  LOADX(fb0, ub0, vb);
  LOADX(fb1, ub1, vb + 1 * dsx);
  LOADX(fb2, ub2, vb + 2 * dsx);
  LOADX(fb3, ub3, vb + 3 * dsx);
  LOADX(fb4, ub4, vb + 4 * dsx);
  XCALC(fb0, ub0, axP);  // ax for step 0

  // 8-step block; CL=true clamps tail prefetch offsets (dead loads, valid addr)
  auto BLOCK = [&](int s, auto CLc) {
    constexpr bool CL = decltype(CLc)::value;
    auto off = [&](int J) { return vb + ((CL && J > 7) ? 7 : J) * dsx; };
    LOADX(fb5, ub5, off(5));
    LOADX(fb6, ub6, off(6));
    STEP(icx<0>{}, fb1, ub1, axP, axQ);
    STEP(icx<1>{}, fb2, ub2, axQ, axP);
    LOADX(fb7, ub7, off(7));
    LOADX(fb0, ub0, off(8));
    STEP(icx<2>{}, fb3, ub3, axP, axQ);
    STEP(icx<3>{}, fb4, ub4, axQ, axP);
    LOADX(fb1, ub1, off(9));
    LOADX(fb2, ub2, off(10));
    STEP(icx<4>{}, fb5, ub5, axP, axQ);
    STEP(icx<5>{}, fb6, ub6, axQ, axP);
    LOADX(fb3, ub3, off(11));
    LOADX(fb4, ub4, off(12));
    STEP(icx<6>{}, fb7, ub7, axP, axQ);
    STEP(icx<7>{}, fb0, ub0, axQ, axP);
    if constexpr (OUTM == 0) flushY8(s); else flushO(s);
  };

#pragma unroll 1
  for (int s = 0; s < 56; s += 8) {
    BLOCK(s, icx<0>{});
    vb += 8 * dsx;
  }
  BLOCK(56, icx<1>{});  // peeled tail: clamped prefetch
}

extern "C" void kernel_launch(void* const* d_in, const int* in_sizes, int n_in,
                              void* d_out, int out_size, void* d_ws, size_t ws_size,
                              hipStream_t stream) {
  const float* x     = (const float*)d_in[0];
  const float* wih1f = (const float*)d_in[1];
  const float* whh1f = (const float*)d_in[2];
  const float* bih1f = (const float*)d_in[3];
  const float* bhh1f = (const float*)d_in[4];
  const float* wih1b = (const float*)d_in[5];
  const float* whh1b = (const float*)d_in[6];
  const float* bih1b = (const float*)d_in[7];
  const float* bhh1b = (const float*)d_in[8];
  const float* wih2f = (const float*)d_in[9];
  const float* whh2f = (const float*)d_in[10];
  const float* bih2f = (const float*)d_in[11];
  const float* bhh2f = (const float*)d_in[12];
  const float* wih2b = (const float*)d_in[13];
  const float* whh2b = (const float*)d_in[14];
  const float* bih2b = (const float*)d_in[15];
  const float* bhh2b = (const float*)d_in[16];
  const float* wih3  = (const float*)d_in[17];
  const float* whh3  = (const float*)d_in[18];
  const float* bih3  = (const float*)d_in[19];
  const float* bhh3  = (const float*)d_in[20];

  using usp = unsigned short*;
  const size_t PL = (size_t)BATCH * T * 16;  // ushorts per plane (padded 16ch)
  usp y1fh = (usp)d_ws;
  usp y1bh = y1fh + PL;
  usp y2fh = y1bh + PL;
  usp y2bh = y2fh + PL;
  float* out = (float*)d_out;

  const dim3 blk(256);
  const dim3 grid_bi(BATCH / 64, 2);   // SEQPW=16 -> 2048 waves
  const dim3 grid_uni(BATCH / 32, 1);  // SEQPW=8  -> 2048 waves (dup rows)

  lstm_k<0, 0, 16><<<grid_bi, blk, 0, stream>>>(
      x, nullptr, nullptr,
      wih1f, whh1f, bih1f, bhh1f, wih1b, whh1b, bih1b, bhh1b,
      y1fh, y1bh, nullptr);
  lstm_k<1, 0, 16><<<grid_bi, blk, 0, stream>>>(
      nullptr, y1fh, y1bh,
      wih2f, whh2f, bih2f, bhh2f, wih2b, whh2b, bih2b, bhh2b,
      y2fh, y2bh, nullptr);
  lstm_k<1, 1, 8><<<grid_uni, blk, 0, stream>>>(
      nullptr, y2fh, y2bh,
      wih3, whh3, bih3, bhh3, wih3, whh3, bih3, bhh3,
      nullptr, nullptr, out);
}